// Round 3
// baseline (1040.676 us; speedup 1.0000x reference)
//
#include <hip/hip_runtime.h>
#include <cstdint>

#define N_NODES   100000
#define N_EDGES   3200000
#define EMB       64
#define NUM_GRAPHS 512

// ---------------- init ----------------
__global__ void init_deg_kernel(float* deg) {
    int i = blockIdx.x * blockDim.x + threadIdx.x;
    if (i < N_NODES) deg[i] = 1.0f;   // self-loop contributes 1
}

// ---------------- degree ----------------
__global__ void deg_kernel(const int* __restrict__ ei, float* __restrict__ deg) {
    int e = blockIdx.x * blockDim.x + threadIdx.x;
    if (e < N_EDGES) {
        int dst = ei[N_EDGES + e];
        atomicAdd(&deg[dst], 1.0f);
    }
}

__global__ void dinv_kernel(float* __restrict__ deg) {
    int i = blockIdx.x * blockDim.x + threadIdx.x;
    if (i < N_NODES) {
        float d = deg[i];               // >= 1 always (self loop)
        deg[i] = 1.0f / sqrtf(d);
    }
}

// ---------------- edge aggregation: wave per edge ----------------
__global__ void agg_kernel(const int* __restrict__ ei,
                           const float* __restrict__ x,
                           const float* __restrict__ dinv,
                           float* __restrict__ agg) {
    int wid  = (blockIdx.x * blockDim.x + threadIdx.x) >> 6;
    int lane = threadIdx.x & 63;
    if (wid >= N_EDGES) return;
    int src = ei[wid];
    int dst = ei[N_EDGES + wid];
    float norm = dinv[src] * dinv[dst];
    float v = x[src * EMB + lane] * norm;
    atomicAdd(&agg[dst * EMB + lane], v);
}

// ---------------- diffuse (in place over agg -> dx) ----------------
__global__ void diffuse_kernel(const float* __restrict__ x,
                               const float* __restrict__ dinv,
                               float* __restrict__ agg) {
    int i = blockIdx.x * blockDim.x + threadIdx.x;   // over float4 elements
    if (i >= N_NODES * (EMB / 4)) return;
    int n = i / (EMB / 4);
    float di = dinv[n];
    float s = di * di;
    float4 xv = ((const float4*)x)[i];
    float4 av = ((float4*)agg)[i];
    float4 r;
    r.x = 0.9f * (av.x + xv.x * s) + 0.1f * xv.x;
    r.y = 0.9f * (av.y + xv.y * s) + 0.1f * xv.y;
    r.z = 0.9f * (av.z + xv.z * s) + 0.1f * xv.z;
    r.w = 0.9f * (av.w + xv.w * s) + 0.1f * xv.w;
    ((float4*)agg)[i] = r;
}

// ---------------- node MLP: wave per node ----------------
__global__ void node_mlp_kernel(const float* __restrict__ dx,
                                const float* __restrict__ wn1,
                                const float* __restrict__ bn1,
                                const float* __restrict__ wn2,
                                const float* __restrict__ bn2,
                                float* __restrict__ gl) {
    __shared__ float wn1s[EMB * EMB];
    __shared__ float bn1s[EMB];
    __shared__ float wn2s[EMB];
    for (int i = threadIdx.x; i < EMB * EMB; i += blockDim.x) wn1s[i] = wn1[i];
    if (threadIdx.x < EMB) { bn1s[threadIdx.x] = bn1[threadIdx.x]; wn2s[threadIdx.x] = wn2[threadIdx.x]; }
    __syncthreads();

    int n = (blockIdx.x * blockDim.x + threadIdx.x) >> 6;
    if (n >= N_NODES) return;
    int j = threadIdx.x & 63;

    float rowv = dx[n * EMB + j];
    float acc = bn1s[j];
#pragma unroll
    for (int c = 0; c < EMB; ++c) {
        float b = __shfl(rowv, c);
        acc += b * wn1s[c * EMB + j];
    }
    float h = fmaxf(acc, 0.0f);
    float t = h * wn2s[j];
#pragma unroll
    for (int off = 32; off; off >>= 1) t += __shfl_xor(t, off);
    if (j == 0) gl[n] = t + bn2[0];
}

// ---------------- softmax over all nodes ----------------
__global__ void smax_pmax_kernel(const float* __restrict__ gl, float* __restrict__ pmax) {
    __shared__ float red[256];
    float m = -1e30f;
    for (int i = blockIdx.x * blockDim.x + threadIdx.x; i < N_NODES; i += gridDim.x * blockDim.x)
        m = fmaxf(m, gl[i]);
    red[threadIdx.x] = m; __syncthreads();
    for (int s = 128; s; s >>= 1) {
        if ((int)threadIdx.x < s) red[threadIdx.x] = fmaxf(red[threadIdx.x], red[threadIdx.x + s]);
        __syncthreads();
    }
    if (threadIdx.x == 0) pmax[blockIdx.x] = red[0];
}

__global__ void smax_fmax_kernel(const float* __restrict__ pmax, float* __restrict__ scal) {
    __shared__ float red[256];
    red[threadIdx.x] = pmax[threadIdx.x]; __syncthreads();
    for (int s = 128; s; s >>= 1) {
        if ((int)threadIdx.x < s) red[threadIdx.x] = fmaxf(red[threadIdx.x], red[threadIdx.x + s]);
        __syncthreads();
    }
    if (threadIdx.x == 0) scal[0] = red[0];
}

__global__ void smax_psum_kernel(const float* __restrict__ gl, const float* __restrict__ scal,
                                 float* __restrict__ psum) {
    __shared__ float red[256];
    float gmax = scal[0];
    float s = 0.0f;
    for (int i = blockIdx.x * blockDim.x + threadIdx.x; i < N_NODES; i += gridDim.x * blockDim.x)
        s += expf(gl[i] - gmax);
    red[threadIdx.x] = s; __syncthreads();
    for (int t = 128; t; t >>= 1) {
        if ((int)threadIdx.x < t) red[threadIdx.x] += red[threadIdx.x + t];
        __syncthreads();
    }
    if (threadIdx.x == 0) psum[blockIdx.x] = red[0];
}

__global__ void smax_fsum_kernel(const float* __restrict__ psum, float* __restrict__ scal) {
    __shared__ float red[256];
    red[threadIdx.x] = psum[threadIdx.x]; __syncthreads();
    for (int t = 128; t; t >>= 1) {
        if ((int)threadIdx.x < t) red[threadIdx.x] += red[threadIdx.x + t];
        __syncthreads();
    }
    if (threadIdx.x == 0) { scal[1] = red[0]; scal[2] = 1.0f / red[0]; }
}

// ---------------- pooling: block per graph (batch is sorted) ----------------
__device__ inline int lower_bound_i(const int* a, int n, int key) {
    int lo = 0, hi = n;
    while (lo < hi) {
        int mid = (lo + hi) >> 1;
        if (a[mid] < key) lo = mid + 1; else hi = mid;
    }
    return lo;
}

__global__ void pool_kernel(const float* __restrict__ dx, const int* __restrict__ batch,
                            float* __restrict__ pooled) {
    int g = blockIdx.x;
    int lo = lower_bound_i(batch, N_NODES, g);
    int hi = lower_bound_i(batch, N_NODES, g + 1);
    int lane = threadIdx.x & 63;
    int w = threadIdx.x >> 6;
    float acc = 0.0f;
    for (int n = lo + w; n < hi; n += 4) acc += dx[n * EMB + lane];
    __shared__ float red[4][EMB];
    red[w][lane] = acc; __syncthreads();
    if (threadIdx.x < EMB) {
        float s = red[0][threadIdx.x] + red[1][threadIdx.x] + red[2][threadIdx.x] + red[3][threadIdx.x];
        int cnt = hi - lo;
        pooled[g * EMB + threadIdx.x] = cnt > 0 ? s / (float)cnt : 0.0f;
    }
}

// ---------------- graph MLP: block per graph (only first 128 cols needed) ----------------
__global__ void graph_mlp_kernel(const float* __restrict__ pooled,
                                 const float* __restrict__ wc1, const float* __restrict__ bc1,
                                 const float* __restrict__ wc2, const float* __restrict__ bc2,
                                 float* __restrict__ alphag) {
    int g = blockIdx.x;
    __shared__ float p[EMB];
    __shared__ float h[EMB];
    if (threadIdx.x < EMB) p[threadIdx.x] = pooled[g * EMB + threadIdx.x];
    __syncthreads();
    if (threadIdx.x < EMB) {
        int j = threadIdx.x;
        float a = bc1[j];
        for (int c = 0; c < EMB; ++c) a += p[c] * wc1[c * EMB + j];
        h[j] = fmaxf(a, 0.0f);
    }
    __syncthreads();
    int o = threadIdx.x;   // 0..127
    float a = bc2[o];
    for (int j = 0; j < EMB; ++j) a += h[j] * wc2[j * 256 + o];
    alphag[g * 128 + o] = tanhf(a);
}

// ---------------- final: wave per node ----------------
__global__ void final_kernel(const float* __restrict__ x, const int* __restrict__ batch,
                             const float* __restrict__ gl, const float* __restrict__ scal,
                             const float* __restrict__ alphag, float* __restrict__ out) {
    int n = (blockIdx.x * blockDim.x + threadIdx.x) >> 6;
    if (n >= N_NODES) return;
    int lane = threadIdx.x & 63;
    int g = batch[n];
    float gamma = expf(gl[n] - scal[0]) * scal[2];
    float a0 = alphag[g * 128 + lane];
    float a1 = alphag[g * 128 + 64 + lane];
    float t = gamma * (x[n * EMB + lane] + 1.0f);
    out[n * EMB + lane] = fmaxf(a0 * t, a1 * t);
}

extern "C" void kernel_launch(void* const* d_in, const int* in_sizes, int n_in,
                              void* d_out, int out_size, void* d_ws, size_t ws_size,
                              hipStream_t stream) {
    const float* x     = (const float*)d_in[0];
    const int*   ei    = (const int*)d_in[1];     // int32 per harness convention
    // d_in[2] edge_attr: unused by the reference
    const int*   batch = (const int*)d_in[3];     // int32 per harness convention
    const float* wn1 = (const float*)d_in[4];
    const float* bn1 = (const float*)d_in[5];
    const float* wn2 = (const float*)d_in[6];
    const float* bn2 = (const float*)d_in[7];
    const float* wc1 = (const float*)d_in[8];
    const float* bc1 = (const float*)d_in[9];
    const float* wc2 = (const float*)d_in[10];
    const float* bc2 = (const float*)d_in[11];
    float* out = (float*)d_out;

    float* ws = (float*)d_ws;
    float* agg    = ws;                           // 6,400,000  (becomes dx in place)
    float* deg    = agg + (size_t)N_NODES * EMB;  // 100,000 (becomes dinv)
    float* gl     = deg + N_NODES;                // 100,000
    float* pmax   = gl + N_NODES;                 // 512
    float* psum   = pmax + 512;                   // 512
    float* scal   = psum + 512;                   // 4
    float* pooled = scal + 4;                     // 32,768
    float* alphag = pooled + NUM_GRAPHS * EMB;    // 65,536

    hipMemsetAsync(agg, 0, (size_t)N_NODES * EMB * sizeof(float), stream);
    init_deg_kernel<<<(N_NODES + 255) / 256, 256, 0, stream>>>(deg);
    deg_kernel<<<(N_EDGES + 255) / 256, 256, 0, stream>>>(ei, deg);
    dinv_kernel<<<(N_NODES + 255) / 256, 256, 0, stream>>>(deg);
    agg_kernel<<<(N_EDGES * 64 + 255) / 256, 256, 0, stream>>>(ei, x, deg, agg);
    diffuse_kernel<<<(N_NODES * (EMB / 4) + 255) / 256, 256, 0, stream>>>(x, deg, agg);
    node_mlp_kernel<<<N_NODES / 4, 256, 0, stream>>>(agg, wn1, bn1, wn2, bn2, gl);
    smax_pmax_kernel<<<256, 256, 0, stream>>>(gl, pmax);
    smax_fmax_kernel<<<1, 256, 0, stream>>>(pmax, scal);
    smax_psum_kernel<<<256, 256, 0, stream>>>(gl, scal, psum);
    smax_fsum_kernel<<<1, 256, 0, stream>>>(psum, scal);
    pool_kernel<<<NUM_GRAPHS, 256, 0, stream>>>(agg, batch, pooled);
    graph_mlp_kernel<<<NUM_GRAPHS, 128, 0, stream>>>(pooled, wc1, bc1, wc2, bc2, alphag);
    final_kernel<<<N_NODES / 4, 256, 0, stream>>>(x, batch, gl, scal, alphag, out);
}

// Round 4
// 769.659 us; speedup vs baseline: 1.3521x; 1.3521x over previous
//
#include <hip/hip_runtime.h>
#include <cstdint>

#define N_NODES   100000
#define N_EDGES   3200000
#define EMB       64
#define NUM_GRAPHS 512
#define SCAN_CHUNK 1024
#define SCAN_NB    ((N_NODES + SCAN_CHUNK - 1) / SCAN_CHUNK)   // 98

// ===================== CSR build =====================
__global__ void hist_kernel(const int* __restrict__ ei, int* __restrict__ indeg) {
    int e = blockIdx.x * blockDim.x + threadIdx.x;
    if (e < N_EDGES) atomicAdd(&indeg[ei[N_EDGES + e]], 1);
}

// block b scans chunk [b*1024, b*1024+1024); writes local EXCLUSIVE scan into
// rowstart, block total into partials[b]
__global__ void scanA_kernel(const int* __restrict__ indeg, int* __restrict__ rowstart,
                             int* __restrict__ partials) {
    __shared__ int s[256];
    int t = threadIdx.x;
    int base = blockIdx.x * SCAN_CHUNK + t * 4;
    int v0 = (base + 0 < N_NODES) ? indeg[base + 0] : 0;
    int v1 = (base + 1 < N_NODES) ? indeg[base + 1] : 0;
    int v2 = (base + 2 < N_NODES) ? indeg[base + 2] : 0;
    int v3 = (base + 3 < N_NODES) ? indeg[base + 3] : 0;
    int p = v0 + v1 + v2 + v3;
    s[t] = p; __syncthreads();
    for (int d = 1; d < 256; d <<= 1) {
        int add = (t >= d) ? s[t - d] : 0;
        __syncthreads();
        s[t] += add;
        __syncthreads();
    }
    int excl = s[t] - p;   // exclusive prefix of this thread's 4-group
    if (base + 0 < N_NODES) rowstart[base + 0] = excl;
    if (base + 1 < N_NODES) rowstart[base + 1] = excl + v0;
    if (base + 2 < N_NODES) rowstart[base + 2] = excl + v0 + v1;
    if (base + 3 < N_NODES) rowstart[base + 3] = excl + v0 + v1 + v2;
    if (t == 255) partials[blockIdx.x] = s[255];
}

__global__ void scanB_kernel(int* __restrict__ partials) {
    __shared__ int s[256];
    int t = threadIdx.x;
    int p = (t < SCAN_NB) ? partials[t] : 0;
    s[t] = p; __syncthreads();
    for (int d = 1; d < 256; d <<= 1) {
        int add = (t >= d) ? s[t - d] : 0;
        __syncthreads();
        s[t] += add;
        __syncthreads();
    }
    if (t < SCAN_NB) partials[t] = s[t] - p;   // exclusive
}

__global__ void scanC_kernel(int* __restrict__ rowstart, int* __restrict__ cursor,
                             const int* __restrict__ partials, const int* __restrict__ indeg,
                             float* __restrict__ dinv) {
    int i = blockIdx.x * blockDim.x + threadIdx.x;
    if (i >= N_NODES) return;
    int rs = rowstart[i] + partials[i >> 10];
    rowstart[i] = rs;
    cursor[i] = rs;
    dinv[i] = rsqrtf((float)(indeg[i] + 1));   // +1 = self loop
}

__global__ void scatter_kernel(const int* __restrict__ ei, int* __restrict__ cursor,
                               int* __restrict__ ebuf) {
    int e = blockIdx.x * blockDim.x + threadIdx.x;
    if (e >= N_EDGES) return;
    int src = ei[e];
    int dst = ei[N_EDGES + e];
    int pos = atomicAdd(&cursor[dst], 1);
    ebuf[pos] = src;
}

// ===================== pull-gather + diffuse fused: wave per node =====================
__global__ void gather_kernel(const int* __restrict__ ebuf, const int* __restrict__ rowstart,
                              const int* __restrict__ indeg, const float* __restrict__ dinv,
                              const float* __restrict__ x, float* __restrict__ dx) {
    int wid  = (blockIdx.x * blockDim.x + threadIdx.x) >> 6;
    int lane = threadIdx.x & 63;
    if (wid >= N_NODES) return;
    int n = __builtin_amdgcn_readfirstlane(wid);
    int start = rowstart[n];
    int cnt   = indeg[n];
    float dn  = dinv[n];
    float acc = 0.0f;
    for (int j = 0; j < cnt; ++j) {
        int src  = ebuf[start + j];
        float nr = dinv[src] * dn;
        acc += x[src * EMB + lane] * nr;
    }
    float xv = x[n * EMB + lane];
    float r  = 0.9f * (acc + xv * dn * dn) + 0.1f * xv;
    dx[n * EMB + lane] = r;
}

// ===================== fallback (push-atomic) path =====================
__global__ void init_deg_kernel(float* deg) {
    int i = blockIdx.x * blockDim.x + threadIdx.x;
    if (i < N_NODES) deg[i] = 1.0f;
}
__global__ void deg_kernel(const int* __restrict__ ei, float* __restrict__ deg) {
    int e = blockIdx.x * blockDim.x + threadIdx.x;
    if (e < N_EDGES) atomicAdd(&deg[ei[N_EDGES + e]], 1.0f);
}
__global__ void dinv_kernel(float* __restrict__ deg) {
    int i = blockIdx.x * blockDim.x + threadIdx.x;
    if (i < N_NODES) deg[i] = 1.0f / sqrtf(deg[i]);
}
__global__ void agg_kernel(const int* __restrict__ ei, const float* __restrict__ x,
                           const float* __restrict__ dinv, float* __restrict__ agg) {
    int wid  = (blockIdx.x * blockDim.x + threadIdx.x) >> 6;
    int lane = threadIdx.x & 63;
    if (wid >= N_EDGES) return;
    int src = ei[wid];
    int dst = ei[N_EDGES + wid];
    float norm = dinv[src] * dinv[dst];
    atomicAdd(&agg[dst * EMB + lane], x[src * EMB + lane] * norm);
}
__global__ void diffuse_kernel(const float* __restrict__ x, const float* __restrict__ dinv,
                               float* __restrict__ agg) {
    int i = blockIdx.x * blockDim.x + threadIdx.x;
    if (i >= N_NODES * (EMB / 4)) return;
    int n = i / (EMB / 4);
    float di = dinv[n];
    float s = di * di;
    float4 xv = ((const float4*)x)[i];
    float4 av = ((float4*)agg)[i];
    float4 r;
    r.x = 0.9f * (av.x + xv.x * s) + 0.1f * xv.x;
    r.y = 0.9f * (av.y + xv.y * s) + 0.1f * xv.y;
    r.z = 0.9f * (av.z + xv.z * s) + 0.1f * xv.z;
    r.w = 0.9f * (av.w + xv.w * s) + 0.1f * xv.w;
    ((float4*)agg)[i] = r;
}

// ===================== node MLP: wave per node =====================
__global__ void node_mlp_kernel(const float* __restrict__ dx,
                                const float* __restrict__ wn1, const float* __restrict__ bn1,
                                const float* __restrict__ wn2, const float* __restrict__ bn2,
                                float* __restrict__ gl) {
    __shared__ float wn1s[EMB * EMB];
    __shared__ float bn1s[EMB];
    __shared__ float wn2s[EMB];
    for (int i = threadIdx.x; i < EMB * EMB; i += blockDim.x) wn1s[i] = wn1[i];
    if (threadIdx.x < EMB) { bn1s[threadIdx.x] = bn1[threadIdx.x]; wn2s[threadIdx.x] = wn2[threadIdx.x]; }
    __syncthreads();
    int n = (blockIdx.x * blockDim.x + threadIdx.x) >> 6;
    if (n >= N_NODES) return;
    int j = threadIdx.x & 63;
    float rowv = dx[n * EMB + j];
    float acc = bn1s[j];
#pragma unroll
    for (int c = 0; c < EMB; ++c) {
        float b = __shfl(rowv, c);
        acc += b * wn1s[c * EMB + j];
    }
    float h = fmaxf(acc, 0.0f);
    float t = h * wn2s[j];
#pragma unroll
    for (int off = 32; off; off >>= 1) t += __shfl_xor(t, off);
    if (j == 0) gl[n] = t + bn2[0];
}

// ===================== softmax reductions =====================
__global__ void smax_pmax_kernel(const float* __restrict__ gl, float* __restrict__ pmax) {
    __shared__ float red[256];
    float m = -1e30f;
    for (int i = blockIdx.x * blockDim.x + threadIdx.x; i < N_NODES; i += gridDim.x * blockDim.x)
        m = fmaxf(m, gl[i]);
    red[threadIdx.x] = m; __syncthreads();
    for (int s = 128; s; s >>= 1) {
        if ((int)threadIdx.x < s) red[threadIdx.x] = fmaxf(red[threadIdx.x], red[threadIdx.x + s]);
        __syncthreads();
    }
    if (threadIdx.x == 0) pmax[blockIdx.x] = red[0];
}
__global__ void smax_fmax_kernel(const float* __restrict__ pmax, float* __restrict__ scal) {
    __shared__ float red[256];
    red[threadIdx.x] = pmax[threadIdx.x]; __syncthreads();
    for (int s = 128; s; s >>= 1) {
        if ((int)threadIdx.x < s) red[threadIdx.x] = fmaxf(red[threadIdx.x], red[threadIdx.x + s]);
        __syncthreads();
    }
    if (threadIdx.x == 0) scal[0] = red[0];
}
__global__ void smax_psum_kernel(const float* __restrict__ gl, const float* __restrict__ scal,
                                 float* __restrict__ psum) {
    __shared__ float red[256];
    float gmax = scal[0];
    float s = 0.0f;
    for (int i = blockIdx.x * blockDim.x + threadIdx.x; i < N_NODES; i += gridDim.x * blockDim.x)
        s += expf(gl[i] - gmax);
    red[threadIdx.x] = s; __syncthreads();
    for (int t = 128; t; t >>= 1) {
        if ((int)threadIdx.x < t) red[threadIdx.x] += red[threadIdx.x + t];
        __syncthreads();
    }
    if (threadIdx.x == 0) psum[blockIdx.x] = red[0];
}
__global__ void smax_fsum_kernel(const float* __restrict__ psum, float* __restrict__ scal) {
    __shared__ float red[256];
    red[threadIdx.x] = psum[threadIdx.x]; __syncthreads();
    for (int t = 128; t; t >>= 1) {
        if ((int)threadIdx.x < t) red[threadIdx.x] += red[threadIdx.x + t];
        __syncthreads();
    }
    if (threadIdx.x == 0) { scal[1] = red[0]; scal[2] = 1.0f / red[0]; }
}

// ===================== pooling =====================
__device__ inline int lower_bound_i(const int* a, int n, int key) {
    int lo = 0, hi = n;
    while (lo < hi) {
        int mid = (lo + hi) >> 1;
        if (a[mid] < key) lo = mid + 1; else hi = mid;
    }
    return lo;
}
__global__ void pool_kernel(const float* __restrict__ dx, const int* __restrict__ batch,
                            float* __restrict__ pooled) {
    int g = blockIdx.x;
    int lo = lower_bound_i(batch, N_NODES, g);
    int hi = lower_bound_i(batch, N_NODES, g + 1);
    int lane = threadIdx.x & 63;
    int w = threadIdx.x >> 6;
    float acc = 0.0f;
    for (int n = lo + w; n < hi; n += 4) acc += dx[n * EMB + lane];
    __shared__ float red[4][EMB];
    red[w][lane] = acc; __syncthreads();
    if (threadIdx.x < EMB) {
        float s = red[0][threadIdx.x] + red[1][threadIdx.x] + red[2][threadIdx.x] + red[3][threadIdx.x];
        int cnt = hi - lo;
        pooled[g * EMB + threadIdx.x] = cnt > 0 ? s / (float)cnt : 0.0f;
    }
}

// ===================== graph MLP =====================
__global__ void graph_mlp_kernel(const float* __restrict__ pooled,
                                 const float* __restrict__ wc1, const float* __restrict__ bc1,
                                 const float* __restrict__ wc2, const float* __restrict__ bc2,
                                 float* __restrict__ alphag) {
    int g = blockIdx.x;
    __shared__ float p[EMB];
    __shared__ float h[EMB];
    if (threadIdx.x < EMB) p[threadIdx.x] = pooled[g * EMB + threadIdx.x];
    __syncthreads();
    if (threadIdx.x < EMB) {
        int j = threadIdx.x;
        float a = bc1[j];
        for (int c = 0; c < EMB; ++c) a += p[c] * wc1[c * EMB + j];
        h[j] = fmaxf(a, 0.0f);
    }
    __syncthreads();
    int o = threadIdx.x;   // 0..127
    float a = bc2[o];
    for (int j = 0; j < EMB; ++j) a += h[j] * wc2[j * 256 + o];
    alphag[g * 128 + o] = tanhf(a);
}

// ===================== final =====================
__global__ void final_kernel(const float* __restrict__ x, const int* __restrict__ batch,
                             const float* __restrict__ gl, const float* __restrict__ scal,
                             const float* __restrict__ alphag, float* __restrict__ out) {
    int n = (blockIdx.x * blockDim.x + threadIdx.x) >> 6;
    if (n >= N_NODES) return;
    int lane = threadIdx.x & 63;
    int g = batch[n];
    float gamma = expf(gl[n] - scal[0]) * scal[2];
    float a0 = alphag[g * 128 + lane];
    float a1 = alphag[g * 128 + 64 + lane];
    float t = gamma * (x[n * EMB + lane] + 1.0f);
    out[n * EMB + lane] = fmaxf(a0 * t, a1 * t);
}

extern "C" void kernel_launch(void* const* d_in, const int* in_sizes, int n_in,
                              void* d_out, int out_size, void* d_ws, size_t ws_size,
                              hipStream_t stream) {
    const float* x     = (const float*)d_in[0];
    const int*   ei    = (const int*)d_in[1];
    const int*   batch = (const int*)d_in[3];
    const float* wn1 = (const float*)d_in[4];
    const float* bn1 = (const float*)d_in[5];
    const float* wn2 = (const float*)d_in[6];
    const float* bn2 = (const float*)d_in[7];
    const float* wc1 = (const float*)d_in[8];
    const float* bc1 = (const float*)d_in[9];
    const float* wc2 = (const float*)d_in[10];
    const float* bc2 = (const float*)d_in[11];
    float* out = (float*)d_out;

    char* wsb = (char*)d_ws;
    // common tail buffers
    float* dx     = (float*)wsb;                        // 6,400,000 f
    float* gl     = dx + (size_t)N_NODES * EMB;         // 100,000
    float* dinv   = gl + N_NODES;                       // 100,000
    float* pooled = dinv + N_NODES;                     // 32,768
    float* alphag = pooled + NUM_GRAPHS * EMB;          // 65,536
    float* pmax   = alphag + NUM_GRAPHS * 128;          // 512
    float* psum   = pmax + 512;                         // 512
    float* scal   = psum + 512;                         // 4
    int* indeg    = (int*)(scal + 4);                   // 100,000
    int* rowstart = indeg + N_NODES;                    // 100,000
    int* cursor   = rowstart + N_NODES;                 // 100,000
    int* partials = cursor + N_NODES;                   // 256
    int* ebuf     = partials + 256;                     // 3,200,000
    size_t needed = (size_t)((char*)(ebuf + N_EDGES) - wsb);

    if (ws_size >= needed) {
        // ---- CSR pull path (no float atomics) ----
        hipMemsetAsync(indeg, 0, N_NODES * sizeof(int), stream);
        hist_kernel<<<(N_EDGES + 255) / 256, 256, 0, stream>>>(ei, indeg);
        scanA_kernel<<<SCAN_NB, 256, 0, stream>>>(indeg, rowstart, partials);
        scanB_kernel<<<1, 256, 0, stream>>>(partials);
        scanC_kernel<<<(N_NODES + 255) / 256, 256, 0, stream>>>(rowstart, cursor, partials, indeg, dinv);
        scatter_kernel<<<(N_EDGES + 255) / 256, 256, 0, stream>>>(ei, cursor, ebuf);
        gather_kernel<<<(N_NODES * 64) / 256, 256, 0, stream>>>(ebuf, rowstart, indeg, dinv, x, dx);
    } else {
        // ---- fallback: push-atomic path (round-3 behavior) ----
        hipMemsetAsync(dx, 0, (size_t)N_NODES * EMB * sizeof(float), stream);
        init_deg_kernel<<<(N_NODES + 255) / 256, 256, 0, stream>>>(dinv);
        deg_kernel<<<(N_EDGES + 255) / 256, 256, 0, stream>>>(ei, dinv);
        dinv_kernel<<<(N_NODES + 255) / 256, 256, 0, stream>>>(dinv);
        agg_kernel<<<((size_t)N_EDGES * 64 + 255) / 256, 256, 0, stream>>>(ei, x, dinv, dx);
        diffuse_kernel<<<(N_NODES * (EMB / 4) + 255) / 256, 256, 0, stream>>>(x, dinv, dx);
    }

    node_mlp_kernel<<<N_NODES / 4, 256, 0, stream>>>(dx, wn1, bn1, wn2, bn2, gl);
    smax_pmax_kernel<<<256, 256, 0, stream>>>(gl, pmax);
    smax_fmax_kernel<<<1, 256, 0, stream>>>(pmax, scal);
    smax_psum_kernel<<<256, 256, 0, stream>>>(gl, scal, psum);
    smax_fsum_kernel<<<1, 256, 0, stream>>>(psum, scal);
    pool_kernel<<<NUM_GRAPHS, 256, 0, stream>>>(dx, batch, pooled);
    graph_mlp_kernel<<<NUM_GRAPHS, 128, 0, stream>>>(pooled, wc1, bc1, wc2, bc2, alphag);
    final_kernel<<<N_NODES / 4, 256, 0, stream>>>(x, batch, gl, scal, alphag, out);
}

// Round 5
// 555.671 us; speedup vs baseline: 1.8728x; 1.3851x over previous
//
#include <hip/hip_runtime.h>
#include <cstdint>

#define N_NODES   100000
#define N_EDGES   3200000
#define EMB       64
#define NUM_GRAPHS 512
#define SCAN_CHUNK 1024
#define SCAN_NB    ((N_NODES + SCAN_CHUNK - 1) / SCAN_CHUNK)   // 98
#define NB        391        // dst-buckets of 256 nodes (ceil(100000/256))
#define PCHUNK    8192       // edges per partition block
#define PBLOCKS   ((N_EDGES + PCHUNK - 1) / PCHUNK)            // 391

// ===================== CSR build =====================
__global__ void hist_kernel(const int* __restrict__ ei, int* __restrict__ indeg) {
    int e = blockIdx.x * blockDim.x + threadIdx.x;
    if (e < N_EDGES) atomicAdd(&indeg[ei[N_EDGES + e]], 1);
}

__global__ void scanA_kernel(const int* __restrict__ indeg, int* __restrict__ rowstart,
                             int* __restrict__ partials) {
    __shared__ int s[256];
    int t = threadIdx.x;
    int base = blockIdx.x * SCAN_CHUNK + t * 4;
    int v0 = (base + 0 < N_NODES) ? indeg[base + 0] : 0;
    int v1 = (base + 1 < N_NODES) ? indeg[base + 1] : 0;
    int v2 = (base + 2 < N_NODES) ? indeg[base + 2] : 0;
    int v3 = (base + 3 < N_NODES) ? indeg[base + 3] : 0;
    int p = v0 + v1 + v2 + v3;
    s[t] = p; __syncthreads();
    for (int d = 1; d < 256; d <<= 1) {
        int add = (t >= d) ? s[t - d] : 0;
        __syncthreads();
        s[t] += add;
        __syncthreads();
    }
    int excl = s[t] - p;
    if (base + 0 < N_NODES) rowstart[base + 0] = excl;
    if (base + 1 < N_NODES) rowstart[base + 1] = excl + v0;
    if (base + 2 < N_NODES) rowstart[base + 2] = excl + v0 + v1;
    if (base + 3 < N_NODES) rowstart[base + 3] = excl + v0 + v1 + v2;
    if (t == 255) partials[blockIdx.x] = s[255];
}

__global__ void scanB_kernel(int* __restrict__ partials) {
    __shared__ int s[256];
    int t = threadIdx.x;
    int p = (t < SCAN_NB) ? partials[t] : 0;
    s[t] = p; __syncthreads();
    for (int d = 1; d < 256; d <<= 1) {
        int add = (t >= d) ? s[t - d] : 0;
        __syncthreads();
        s[t] += add;
        __syncthreads();
    }
    if (t < SCAN_NB) partials[t] = s[t] - p;
}

// finalize rowstart; init bucket cursors (bcur[b] = rowstart[b<<8]); dinv
__global__ void scanC_kernel(int* __restrict__ rowstart, int* __restrict__ bcur,
                             const int* __restrict__ partials, const int* __restrict__ indeg,
                             float* __restrict__ dinv) {
    int i = blockIdx.x * blockDim.x + threadIdx.x;
    if (i >= N_NODES) return;
    int rs = rowstart[i] + partials[i >> 10];
    rowstart[i] = rs;
    if ((i & 255) == 0) bcur[i >> 8] = rs;
    dinv[i] = rsqrtf((float)(indeg[i] + 1));   // +1 = self loop
}

// ---- phase 1: partition (src,dst) pairs into dst-buckets, coalesced writes ----
__global__ void partition_kernel(const int* __restrict__ ei, int* __restrict__ bcur,
                                 uint2* __restrict__ gpairs) {
    __shared__ uint2 sp[PCHUNK];       // 64 KB
    __shared__ int scnt[512];
    __shared__ int soff[512];
    __shared__ int scur[512];
    __shared__ int gbase[512];
    __shared__ int s[256];
    int t = threadIdx.x;
    for (int i = t; i < 512; i += 256) scnt[i] = 0;
    __syncthreads();
    int base = blockIdx.x * PCHUNK;
    int lim  = min(N_EDGES - base, PCHUNK);
    // pass 1: local bucket counts
    for (int k = t; k < lim; k += 256) {
        int d = ei[N_EDGES + base + k];
        atomicAdd(&scnt[d >> 8], 1);
    }
    __syncthreads();
    // exclusive scan of 512 bucket counts (2 per thread)
    int a0 = scnt[2 * t], a1 = scnt[2 * t + 1];
    int p = a0 + a1;
    s[t] = p; __syncthreads();
    for (int d = 1; d < 256; d <<= 1) {
        int add = (t >= d) ? s[t - d] : 0;
        __syncthreads();
        s[t] += add;
        __syncthreads();
    }
    int excl = s[t] - p;
    soff[2 * t] = excl;       soff[2 * t + 1] = excl + a0;
    scur[2 * t] = excl;       scur[2 * t + 1] = excl + a0;
    __syncthreads();
    // reserve global space per bucket
    for (int i = t; i < NB; i += 256) gbase[i] = atomicAdd(&bcur[i], scnt[i]);
    __syncthreads();
    // pass 2: place pairs grouped in LDS
    for (int k = t; k < lim; k += 256) {
        int sId = ei[base + k];
        int d   = ei[N_EDGES + base + k];
        int pos = atomicAdd(&scur[d >> 8], 1);
        sp[pos] = make_uint2((unsigned)sId, (unsigned)d);
    }
    __syncthreads();
    // write out: consecutive i within a bucket -> consecutive global positions
    for (int i = t; i < lim; i += 256) {
        uint2 pr = sp[i];
        int b = (int)(pr.y >> 8);
        gpairs[gbase[b] + (i - soff[b])] = pr;
    }
}

// ---- phase 2: per-bucket scatter with LDS cursors (writes stay in a 32KB L2 window) ----
__global__ void bscatter_kernel(const uint2* __restrict__ gpairs,
                                const int* __restrict__ rowstart,
                                int* __restrict__ ebuf) {
    int b   = blockIdx.x;
    int nlo = b << 8;
    __shared__ int lcur[256];
    int t = threadIdx.x;
    int n = nlo + t;
    lcur[t] = (n < N_NODES) ? rowstart[n] : 0;
    __syncthreads();
    int base = rowstart[nlo];
    int end  = (b == NB - 1) ? N_EDGES : rowstart[nlo + 256];
    int cnt  = end - base;
    for (int i = t; i < cnt; i += 256) {
        uint2 pr = gpairs[base + i];
        int pos = atomicAdd(&lcur[pr.y & 255], 1);
        ebuf[pos] = (int)pr.x;
    }
}

// ===================== pull-gather + diffuse fused: wave per node =====================
__global__ void gather_kernel(const int* __restrict__ ebuf, const int* __restrict__ rowstart,
                              const int* __restrict__ indeg, const float* __restrict__ dinv,
                              const float* __restrict__ x, float* __restrict__ dx) {
    int wid  = (blockIdx.x * blockDim.x + threadIdx.x) >> 6;
    int lane = threadIdx.x & 63;
    if (wid >= N_NODES) return;
    int n = __builtin_amdgcn_readfirstlane(wid);
    int start = rowstart[n];
    int cnt   = indeg[n];
    float dn  = dinv[n];
    float acc = 0.0f;
    for (int j = 0; j < cnt; ++j) {
        int src  = ebuf[start + j];
        float nr = dinv[src] * dn;
        acc += x[src * EMB + lane] * nr;
    }
    float xv = x[n * EMB + lane];
    float r  = 0.9f * (acc + xv * dn * dn) + 0.1f * xv;
    dx[n * EMB + lane] = r;
}

// ===================== fallback (push-atomic) path =====================
__global__ void init_deg_kernel(float* deg) {
    int i = blockIdx.x * blockDim.x + threadIdx.x;
    if (i < N_NODES) deg[i] = 1.0f;
}
__global__ void deg_kernel(const int* __restrict__ ei, float* __restrict__ deg) {
    int e = blockIdx.x * blockDim.x + threadIdx.x;
    if (e < N_EDGES) atomicAdd(&deg[ei[N_EDGES + e]], 1.0f);
}
__global__ void dinv_kernel(float* __restrict__ deg) {
    int i = blockIdx.x * blockDim.x + threadIdx.x;
    if (i < N_NODES) deg[i] = 1.0f / sqrtf(deg[i]);
}
__global__ void agg_kernel(const int* __restrict__ ei, const float* __restrict__ x,
                           const float* __restrict__ dinv, float* __restrict__ agg) {
    int wid  = (blockIdx.x * blockDim.x + threadIdx.x) >> 6;
    int lane = threadIdx.x & 63;
    if (wid >= N_EDGES) return;
    int src = ei[wid];
    int dst = ei[N_EDGES + wid];
    float norm = dinv[src] * dinv[dst];
    atomicAdd(&agg[dst * EMB + lane], x[src * EMB + lane] * norm);
}
__global__ void diffuse_kernel(const float* __restrict__ x, const float* __restrict__ dinv,
                               float* __restrict__ agg) {
    int i = blockIdx.x * blockDim.x + threadIdx.x;
    if (i >= N_NODES * (EMB / 4)) return;
    int n = i / (EMB / 4);
    float di = dinv[n];
    float s = di * di;
    float4 xv = ((const float4*)x)[i];
    float4 av = ((float4*)agg)[i];
    float4 r;
    r.x = 0.9f * (av.x + xv.x * s) + 0.1f * xv.x;
    r.y = 0.9f * (av.y + xv.y * s) + 0.1f * xv.y;
    r.z = 0.9f * (av.z + xv.z * s) + 0.1f * xv.z;
    r.w = 0.9f * (av.w + xv.w * s) + 0.1f * xv.w;
    ((float4*)agg)[i] = r;
}

// ===================== node MLP: wave per node =====================
__global__ void node_mlp_kernel(const float* __restrict__ dx,
                                const float* __restrict__ wn1, const float* __restrict__ bn1,
                                const float* __restrict__ wn2, const float* __restrict__ bn2,
                                float* __restrict__ gl) {
    __shared__ float wn1s[EMB * EMB];
    __shared__ float bn1s[EMB];
    __shared__ float wn2s[EMB];
    for (int i = threadIdx.x; i < EMB * EMB; i += blockDim.x) wn1s[i] = wn1[i];
    if (threadIdx.x < EMB) { bn1s[threadIdx.x] = bn1[threadIdx.x]; wn2s[threadIdx.x] = wn2[threadIdx.x]; }
    __syncthreads();
    int n = (blockIdx.x * blockDim.x + threadIdx.x) >> 6;
    if (n >= N_NODES) return;
    int j = threadIdx.x & 63;
    float rowv = dx[n * EMB + j];
    float acc = bn1s[j];
#pragma unroll
    for (int c = 0; c < EMB; ++c) {
        float b = __shfl(rowv, c);
        acc += b * wn1s[c * EMB + j];
    }
    float h = fmaxf(acc, 0.0f);
    float t = h * wn2s[j];
#pragma unroll
    for (int off = 32; off; off >>= 1) t += __shfl_xor(t, off);
    if (j == 0) gl[n] = t + bn2[0];
}

// ===================== softmax reductions =====================
__global__ void smax_pmax_kernel(const float* __restrict__ gl, float* __restrict__ pmax) {
    __shared__ float red[256];
    float m = -1e30f;
    for (int i = blockIdx.x * blockDim.x + threadIdx.x; i < N_NODES; i += gridDim.x * blockDim.x)
        m = fmaxf(m, gl[i]);
    red[threadIdx.x] = m; __syncthreads();
    for (int s = 128; s; s >>= 1) {
        if ((int)threadIdx.x < s) red[threadIdx.x] = fmaxf(red[threadIdx.x], red[threadIdx.x + s]);
        __syncthreads();
    }
    if (threadIdx.x == 0) pmax[blockIdx.x] = red[0];
}
__global__ void smax_fmax_kernel(const float* __restrict__ pmax, float* __restrict__ scal) {
    __shared__ float red[256];
    red[threadIdx.x] = pmax[threadIdx.x]; __syncthreads();
    for (int s = 128; s; s >>= 1) {
        if ((int)threadIdx.x < s) red[threadIdx.x] = fmaxf(red[threadIdx.x], red[threadIdx.x + s]);
        __syncthreads();
    }
    if (threadIdx.x == 0) scal[0] = red[0];
}
__global__ void smax_psum_kernel(const float* __restrict__ gl, const float* __restrict__ scal,
                                 float* __restrict__ psum) {
    __shared__ float red[256];
    float gmax = scal[0];
    float s = 0.0f;
    for (int i = blockIdx.x * blockDim.x + threadIdx.x; i < N_NODES; i += gridDim.x * blockDim.x)
        s += expf(gl[i] - gmax);
    red[threadIdx.x] = s; __syncthreads();
    for (int t = 128; t; t >>= 1) {
        if ((int)threadIdx.x < t) red[threadIdx.x] += red[threadIdx.x + t];
        __syncthreads();
    }
    if (threadIdx.x == 0) psum[blockIdx.x] = red[0];
}
__global__ void smax_fsum_kernel(const float* __restrict__ psum, float* __restrict__ scal) {
    __shared__ float red[256];
    red[threadIdx.x] = psum[threadIdx.x]; __syncthreads();
    for (int t = 128; t; t >>= 1) {
        if ((int)threadIdx.x < t) red[threadIdx.x] += red[threadIdx.x + t];
        __syncthreads();
    }
    if (threadIdx.x == 0) { scal[1] = red[0]; scal[2] = 1.0f / red[0]; }
}

// ===================== pooling =====================
__device__ inline int lower_bound_i(const int* a, int n, int key) {
    int lo = 0, hi = n;
    while (lo < hi) {
        int mid = (lo + hi) >> 1;
        if (a[mid] < key) lo = mid + 1; else hi = mid;
    }
    return lo;
}
__global__ void pool_kernel(const float* __restrict__ dx, const int* __restrict__ batch,
                            float* __restrict__ pooled) {
    int g = blockIdx.x;
    int lo = lower_bound_i(batch, N_NODES, g);
    int hi = lower_bound_i(batch, N_NODES, g + 1);
    int lane = threadIdx.x & 63;
    int w = threadIdx.x >> 6;
    float acc = 0.0f;
    for (int n = lo + w; n < hi; n += 4) acc += dx[n * EMB + lane];
    __shared__ float red[4][EMB];
    red[w][lane] = acc; __syncthreads();
    if (threadIdx.x < EMB) {
        float s = red[0][threadIdx.x] + red[1][threadIdx.x] + red[2][threadIdx.x] + red[3][threadIdx.x];
        int cnt = hi - lo;
        pooled[g * EMB + threadIdx.x] = cnt > 0 ? s / (float)cnt : 0.0f;
    }
}

// ===================== graph MLP =====================
__global__ void graph_mlp_kernel(const float* __restrict__ pooled,
                                 const float* __restrict__ wc1, const float* __restrict__ bc1,
                                 const float* __restrict__ wc2, const float* __restrict__ bc2,
                                 float* __restrict__ alphag) {
    int g = blockIdx.x;
    __shared__ float p[EMB];
    __shared__ float h[EMB];
    if (threadIdx.x < EMB) p[threadIdx.x] = pooled[g * EMB + threadIdx.x];
    __syncthreads();
    if (threadIdx.x < EMB) {
        int j = threadIdx.x;
        float a = bc1[j];
        for (int c = 0; c < EMB; ++c) a += p[c] * wc1[c * EMB + j];
        h[j] = fmaxf(a, 0.0f);
    }
    __syncthreads();
    int o = threadIdx.x;   // 0..127
    float a = bc2[o];
    for (int j = 0; j < EMB; ++j) a += h[j] * wc2[j * 256 + o];
    alphag[g * 128 + o] = tanhf(a);
}

// ===================== final =====================
__global__ void final_kernel(const float* __restrict__ x, const int* __restrict__ batch,
                             const float* __restrict__ gl, const float* __restrict__ scal,
                             const float* __restrict__ alphag, float* __restrict__ out) {
    int n = (blockIdx.x * blockDim.x + threadIdx.x) >> 6;
    if (n >= N_NODES) return;
    int lane = threadIdx.x & 63;
    int g = batch[n];
    float gamma = expf(gl[n] - scal[0]) * scal[2];
    float a0 = alphag[g * 128 + lane];
    float a1 = alphag[g * 128 + 64 + lane];
    float t = gamma * (x[n * EMB + lane] + 1.0f);
    out[n * EMB + lane] = fmaxf(a0 * t, a1 * t);
}

extern "C" void kernel_launch(void* const* d_in, const int* in_sizes, int n_in,
                              void* d_out, int out_size, void* d_ws, size_t ws_size,
                              hipStream_t stream) {
    const float* x     = (const float*)d_in[0];
    const int*   ei    = (const int*)d_in[1];
    const int*   batch = (const int*)d_in[3];
    const float* wn1 = (const float*)d_in[4];
    const float* bn1 = (const float*)d_in[5];
    const float* wn2 = (const float*)d_in[6];
    const float* bn2 = (const float*)d_in[7];
    const float* wc1 = (const float*)d_in[8];
    const float* bc1 = (const float*)d_in[9];
    const float* wc2 = (const float*)d_in[10];
    const float* bc2 = (const float*)d_in[11];
    float* out = (float*)d_out;

    char* wsb = (char*)d_ws;
    float* dx     = (float*)wsb;                        // 6,400,000 f  (aliases gpairs)
    float* gl     = dx + (size_t)N_NODES * EMB;         // 100,000
    float* dinv   = gl + N_NODES;                       // 100,000
    float* pooled = dinv + N_NODES;                     // 32,768
    float* alphag = pooled + NUM_GRAPHS * EMB;          // 65,536
    float* pmax   = alphag + NUM_GRAPHS * 128;          // 512
    float* psum   = pmax + 512;                         // 512
    float* scal   = psum + 512;                         // 4
    int* indeg    = (int*)(scal + 4);                   // 100,000
    int* rowstart = indeg + N_NODES;                    // 100,000
    int* bcur     = rowstart + N_NODES;                 // 512
    int* partials = bcur + 512;                         // 256
    int* ebuf     = partials + 256;                     // 3,200,000
    size_t needed = (size_t)((char*)(ebuf + N_EDGES) - wsb);
    uint2* gpairs = (uint2*)dx;                         // aliases dx (consumed before gather writes)

    if (ws_size >= needed) {
        // ---- CSR pull path (no float atomics, L2-friendly scatter) ----
        hipMemsetAsync(indeg, 0, N_NODES * sizeof(int), stream);
        hist_kernel<<<(N_EDGES + 255) / 256, 256, 0, stream>>>(ei, indeg);
        scanA_kernel<<<SCAN_NB, 256, 0, stream>>>(indeg, rowstart, partials);
        scanB_kernel<<<1, 256, 0, stream>>>(partials);
        scanC_kernel<<<(N_NODES + 255) / 256, 256, 0, stream>>>(rowstart, bcur, partials, indeg, dinv);
        partition_kernel<<<PBLOCKS, 256, 0, stream>>>(ei, bcur, gpairs);
        bscatter_kernel<<<NB, 256, 0, stream>>>(gpairs, rowstart, ebuf);
        gather_kernel<<<(N_NODES * 64) / 256, 256, 0, stream>>>(ebuf, rowstart, indeg, dinv, x, dx);
    } else {
        // ---- fallback: push-atomic path ----
        hipMemsetAsync(dx, 0, (size_t)N_NODES * EMB * sizeof(float), stream);
        init_deg_kernel<<<(N_NODES + 255) / 256, 256, 0, stream>>>(dinv);
        deg_kernel<<<(N_EDGES + 255) / 256, 256, 0, stream>>>(ei, dinv);
        dinv_kernel<<<(N_NODES + 255) / 256, 256, 0, stream>>>(dinv);
        agg_kernel<<<((size_t)N_EDGES * 64 + 255) / 256, 256, 0, stream>>>(ei, x, dinv, dx);
        diffuse_kernel<<<(N_NODES * (EMB / 4) + 255) / 256, 256, 0, stream>>>(x, dinv, dx);
    }

    node_mlp_kernel<<<N_NODES / 4, 256, 0, stream>>>(dx, wn1, bn1, wn2, bn2, gl);
    smax_pmax_kernel<<<256, 256, 0, stream>>>(gl, pmax);
    smax_fmax_kernel<<<1, 256, 0, stream>>>(pmax, scal);
    smax_psum_kernel<<<256, 256, 0, stream>>>(gl, scal, psum);
    smax_fsum_kernel<<<1, 256, 0, stream>>>(psum, scal);
    pool_kernel<<<NUM_GRAPHS, 256, 0, stream>>>(dx, batch, pooled);
    graph_mlp_kernel<<<NUM_GRAPHS, 128, 0, stream>>>(pooled, wc1, bc1, wc2, bc2, alphag);
    final_kernel<<<N_NODES / 4, 256, 0, stream>>>(x, batch, gl, scal, alphag, out);
}

// Round 6
// 458.111 us; speedup vs baseline: 2.2717x; 1.2130x over previous
//
#include <hip/hip_runtime.h>
#include <cstdint>

#define N_NODES   100000
#define N_EDGES   3200000
#define EMB       64
#define NUM_GRAPHS 512
#define SCAN_CHUNK 1024
#define SCAN_NB    ((N_NODES + SCAN_CHUNK - 1) / SCAN_CHUNK)   // 98
#define NB        391        // dst-buckets of 256 nodes
#define PCHUNK    8192       // edges per partition block
#define PBLOCKS   ((N_EDGES + PCHUNK - 1) / PCHUNK)            // 391

// ===================== CSR build =====================
__global__ void hist_kernel(const int* __restrict__ ei, int* __restrict__ indeg) {
    int e = blockIdx.x * blockDim.x + threadIdx.x;
    if (e < N_EDGES) atomicAdd(&indeg[ei[N_EDGES + e]], 1);
}

__global__ void scanA_kernel(const int* __restrict__ indeg, int* __restrict__ rowstart,
                             int* __restrict__ partials) {
    __shared__ int s[256];
    int t = threadIdx.x;
    int base = blockIdx.x * SCAN_CHUNK + t * 4;
    int v0 = (base + 0 < N_NODES) ? indeg[base + 0] : 0;
    int v1 = (base + 1 < N_NODES) ? indeg[base + 1] : 0;
    int v2 = (base + 2 < N_NODES) ? indeg[base + 2] : 0;
    int v3 = (base + 3 < N_NODES) ? indeg[base + 3] : 0;
    int p = v0 + v1 + v2 + v3;
    s[t] = p; __syncthreads();
    for (int d = 1; d < 256; d <<= 1) {
        int add = (t >= d) ? s[t - d] : 0;
        __syncthreads();
        s[t] += add;
        __syncthreads();
    }
    int excl = s[t] - p;
    if (base + 0 < N_NODES) rowstart[base + 0] = excl;
    if (base + 1 < N_NODES) rowstart[base + 1] = excl + v0;
    if (base + 2 < N_NODES) rowstart[base + 2] = excl + v0 + v1;
    if (base + 3 < N_NODES) rowstart[base + 3] = excl + v0 + v1 + v2;
    if (t == 255) partials[blockIdx.x] = s[255];
}

__global__ void scanB_kernel(int* __restrict__ partials) {
    __shared__ int s[256];
    int t = threadIdx.x;
    int p = (t < SCAN_NB) ? partials[t] : 0;
    s[t] = p; __syncthreads();
    for (int d = 1; d < 256; d <<= 1) {
        int add = (t >= d) ? s[t - d] : 0;
        __syncthreads();
        s[t] += add;
        __syncthreads();
    }
    if (t < SCAN_NB) partials[t] = s[t] - p;
}

__global__ void scanC_kernel(int* __restrict__ rowstart, int* __restrict__ bcur,
                             const int* __restrict__ partials, const int* __restrict__ indeg,
                             float* __restrict__ dinv) {
    int i = blockIdx.x * blockDim.x + threadIdx.x;
    if (i >= N_NODES) return;
    int rs = rowstart[i] + partials[i >> 10];
    rowstart[i] = rs;
    if ((i & 255) == 0) bcur[i >> 8] = rs;
    dinv[i] = rsqrtf((float)(indeg[i] + 1));   // +1 = self loop
}

// ---- phase 1: partition packed (src | local-dst) into dst-buckets ----
__global__ void partition_kernel(const int* __restrict__ ei, int* __restrict__ bcur,
                                 unsigned* __restrict__ gpairs) {
    __shared__ unsigned sp[PCHUNK];    // 32 KB
    __shared__ int scnt[512];
    __shared__ int soff[512];
    __shared__ int scur[512];
    __shared__ int gbase[512];
    __shared__ int s[256];
    int t = threadIdx.x;
    for (int i = t; i < 512; i += 256) scnt[i] = 0;
    __syncthreads();
    int base = blockIdx.x * PCHUNK;
    int lim  = min(N_EDGES - base, PCHUNK);
    for (int k = t; k < lim; k += 256) {
        int d = ei[N_EDGES + base + k];
        atomicAdd(&scnt[d >> 8], 1);
    }
    __syncthreads();
    int a0 = scnt[2 * t], a1 = scnt[2 * t + 1];
    int p = a0 + a1;
    s[t] = p; __syncthreads();
    for (int d = 1; d < 256; d <<= 1) {
        int add = (t >= d) ? s[t - d] : 0;
        __syncthreads();
        s[t] += add;
        __syncthreads();
    }
    int excl = s[t] - p;
    soff[2 * t] = excl;       soff[2 * t + 1] = excl + a0;
    scur[2 * t] = excl;       scur[2 * t + 1] = excl + a0;
    __syncthreads();
    for (int i = t; i < NB; i += 256) gbase[i] = atomicAdd(&bcur[i], scnt[i]);
    __syncthreads();
    for (int k = t; k < lim; k += 256) {
        int sId = ei[base + k];
        int d   = ei[N_EDGES + base + k];
        int pos = atomicAdd(&scur[d >> 8], 1);
        sp[pos] = (unsigned)sId | ((unsigned)(d & 255) << 17);   // src:17b, local dst:8b
    }
    __syncthreads();
    for (int i = t; i < lim; i += 256) {
        unsigned pk = sp[i];
        // bucket = last b with soff[b] <= i  (soff non-decreasing)
        int lo = 0, hi = NB - 1;
        while (lo < hi) { int mid = (lo + hi + 1) >> 1; if (soff[mid] <= i) lo = mid; else hi = mid - 1; }
        gpairs[gbase[lo] + (i - soff[lo])] = pk;
    }
}

// ---- phase 2: per-bucket scatter with LDS cursors ----
__global__ void bscatter_kernel(const unsigned* __restrict__ gpairs,
                                const int* __restrict__ rowstart,
                                int* __restrict__ ebuf) {
    int b   = blockIdx.x;
    int nlo = b << 8;
    __shared__ int lcur[256];
    int t = threadIdx.x;
    int n = nlo + t;
    lcur[t] = (n < N_NODES) ? rowstart[n] : 0;
    __syncthreads();
    int base = rowstart[nlo];
    int end  = (b == NB - 1) ? N_EDGES : rowstart[nlo + 256];
    int cnt  = end - base;
    for (int i = t; i < cnt; i += 256) {
        unsigned pk = gpairs[base + i];
        int pos = atomicAdd(&lcur[(pk >> 17) & 255], 1);
        ebuf[pos] = (int)(pk & 0x1FFFFu);
    }
}

// ===================== gather + diffuse + node-MLP fused: wave per node =====================
// lane l: edge-group g = l>>4 (4 edges in flight), float4 column q = l&15.
__global__ void gather_mlp_kernel(const int* __restrict__ ebuf, const int* __restrict__ rowstart,
                                  const int* __restrict__ indeg, const float* __restrict__ dinv,
                                  const float* __restrict__ x, float* __restrict__ dx,
                                  const float* __restrict__ wn1, const float* __restrict__ bn1,
                                  const float* __restrict__ wn2, const float* __restrict__ bn2,
                                  float* __restrict__ gl) {
    __shared__ float wn1s[EMB * EMB];
    __shared__ float bn1s[EMB];
    __shared__ float wn2s[EMB];
    for (int i = threadIdx.x; i < EMB * EMB; i += blockDim.x) wn1s[i] = wn1[i];
    if (threadIdx.x < EMB) { bn1s[threadIdx.x] = bn1[threadIdx.x]; wn2s[threadIdx.x] = wn2[threadIdx.x]; }
    __syncthreads();

    int wid = (blockIdx.x * blockDim.x + threadIdx.x) >> 6;
    if (wid >= N_NODES) return;
    int n = __builtin_amdgcn_readfirstlane(wid);
    int l = threadIdx.x & 63;
    int g = l >> 4;
    int q = l & 15;
    int start = rowstart[n];
    int cnt   = indeg[n];
    float dn  = dinv[n];
    const float4* __restrict__ x4 = (const float4*)x;

    float ax = 0.f, ay = 0.f, az = 0.f, aw = 0.f;
    int j = 0;
    for (; j + 8 <= cnt; j += 8) {            // 8 rows in flight per wave
        int sA = ebuf[start + j + g];
        int sB = ebuf[start + j + 4 + g];
        float wA = dinv[sA] * dn;
        float wB = dinv[sB] * dn;
        float4 vA = x4[sA * 16 + q];
        float4 vB = x4[sB * 16 + q];
        ax += vA.x * wA + vB.x * wB;
        ay += vA.y * wA + vB.y * wB;
        az += vA.z * wA + vB.z * wB;
        aw += vA.w * wA + vB.w * wB;
    }
    if (j + 4 <= cnt) {
        int sA = ebuf[start + j + g];
        float wA = dinv[sA] * dn;
        float4 vA = x4[sA * 16 + q];
        ax += vA.x * wA; ay += vA.y * wA; az += vA.z * wA; aw += vA.w * wA;
        j += 4;
    }
    int rem = cnt - j;
    if (g < rem) {
        int sA = ebuf[start + j + g];
        float wA = dinv[sA] * dn;
        float4 vA = x4[sA * 16 + q];
        ax += vA.x * wA; ay += vA.y * wA; az += vA.z * wA; aw += vA.w * wA;
    }
    // reduce across the 4 edge-groups
    ax += __shfl_xor(ax, 16); ax += __shfl_xor(ax, 32);
    ay += __shfl_xor(ay, 16); ay += __shfl_xor(ay, 32);
    az += __shfl_xor(az, 16); az += __shfl_xor(az, 32);
    aw += __shfl_xor(aw, 16); aw += __shfl_xor(aw, 32);

    // diffuse
    float4 xv = x4[n * 16 + q];
    float s2 = dn * dn;
    float r0 = 0.9f * (ax + xv.x * s2) + 0.1f * xv.x;
    float r1 = 0.9f * (ay + xv.y * s2) + 0.1f * xv.y;
    float r2 = 0.9f * (az + xv.z * s2) + 0.1f * xv.z;
    float r3 = 0.9f * (aw + xv.w * s2) + 0.1f * xv.w;
    if (l < 16) {
        float4 rv; rv.x = r0; rv.y = r1; rv.z = r2; rv.w = r3;
        ((float4*)dx)[n * 16 + q] = rv;
    }

    // node MLP: lane l computes hidden column l (dx row distributed: lane s holds ch 4s..4s+3)
    float rr[4] = {r0, r1, r2, r3};
    float am = bn1s[l];
#pragma unroll
    for (int c = 0; c < EMB; ++c) {
        float b = __shfl(rr[c & 3], c >> 2);
        am += b * wn1s[c * EMB + l];
    }
    float h = fmaxf(am, 0.0f);
    float t = h * wn2s[l];
#pragma unroll
    for (int off = 32; off; off >>= 1) t += __shfl_xor(t, off);
    if (l == 0) gl[n] = t + bn2[0];
}

// ===================== fallback (push-atomic) path =====================
__global__ void init_deg_kernel(float* deg) {
    int i = blockIdx.x * blockDim.x + threadIdx.x;
    if (i < N_NODES) deg[i] = 1.0f;
}
__global__ void deg_kernel(const int* __restrict__ ei, float* __restrict__ deg) {
    int e = blockIdx.x * blockDim.x + threadIdx.x;
    if (e < N_EDGES) atomicAdd(&deg[ei[N_EDGES + e]], 1.0f);
}
__global__ void dinv_kernel(float* __restrict__ deg) {
    int i = blockIdx.x * blockDim.x + threadIdx.x;
    if (i < N_NODES) deg[i] = 1.0f / sqrtf(deg[i]);
}
__global__ void agg_kernel(const int* __restrict__ ei, const float* __restrict__ x,
                           const float* __restrict__ dinv, float* __restrict__ agg) {
    int wid  = (blockIdx.x * blockDim.x + threadIdx.x) >> 6;
    int lane = threadIdx.x & 63;
    if (wid >= N_EDGES) return;
    int src = ei[wid];
    int dst = ei[N_EDGES + wid];
    float norm = dinv[src] * dinv[dst];
    atomicAdd(&agg[dst * EMB + lane], x[src * EMB + lane] * norm);
}
__global__ void diffuse_kernel(const float* __restrict__ x, const float* __restrict__ dinv,
                               float* __restrict__ agg) {
    int i = blockIdx.x * blockDim.x + threadIdx.x;
    if (i >= N_NODES * (EMB / 4)) return;
    int n = i / (EMB / 4);
    float di = dinv[n];
    float s = di * di;
    float4 xv = ((const float4*)x)[i];
    float4 av = ((float4*)agg)[i];
    float4 r;
    r.x = 0.9f * (av.x + xv.x * s) + 0.1f * xv.x;
    r.y = 0.9f * (av.y + xv.y * s) + 0.1f * xv.y;
    r.z = 0.9f * (av.z + xv.z * s) + 0.1f * xv.z;
    r.w = 0.9f * (av.w + xv.w * s) + 0.1f * xv.w;
    ((float4*)agg)[i] = r;
}
__global__ void node_mlp_kernel(const float* __restrict__ dx,
                                const float* __restrict__ wn1, const float* __restrict__ bn1,
                                const float* __restrict__ wn2, const float* __restrict__ bn2,
                                float* __restrict__ gl) {
    __shared__ float wn1s[EMB * EMB];
    __shared__ float bn1s[EMB];
    __shared__ float wn2s[EMB];
    for (int i = threadIdx.x; i < EMB * EMB; i += blockDim.x) wn1s[i] = wn1[i];
    if (threadIdx.x < EMB) { bn1s[threadIdx.x] = bn1[threadIdx.x]; wn2s[threadIdx.x] = wn2[threadIdx.x]; }
    __syncthreads();
    int n = (blockIdx.x * blockDim.x + threadIdx.x) >> 6;
    if (n >= N_NODES) return;
    int j = threadIdx.x & 63;
    float rowv = dx[n * EMB + j];
    float acc = bn1s[j];
#pragma unroll
    for (int c = 0; c < EMB; ++c) {
        float b = __shfl(rowv, c);
        acc += b * wn1s[c * EMB + j];
    }
    float h = fmaxf(acc, 0.0f);
    float t = h * wn2s[j];
#pragma unroll
    for (int off = 32; off; off >>= 1) t += __shfl_xor(t, off);
    if (j == 0) gl[n] = t + bn2[0];
}

// ===================== softmax reductions =====================
__global__ void smax_pmax_kernel(const float* __restrict__ gl, float* __restrict__ pmax) {
    __shared__ float red[256];
    float m = -1e30f;
    for (int i = blockIdx.x * blockDim.x + threadIdx.x; i < N_NODES; i += gridDim.x * blockDim.x)
        m = fmaxf(m, gl[i]);
    red[threadIdx.x] = m; __syncthreads();
    for (int s = 128; s; s >>= 1) {
        if ((int)threadIdx.x < s) red[threadIdx.x] = fmaxf(red[threadIdx.x], red[threadIdx.x + s]);
        __syncthreads();
    }
    if (threadIdx.x == 0) pmax[blockIdx.x] = red[0];
}
__global__ void smax_fmax_kernel(const float* __restrict__ pmax, float* __restrict__ scal) {
    __shared__ float red[256];
    red[threadIdx.x] = pmax[threadIdx.x]; __syncthreads();
    for (int s = 128; s; s >>= 1) {
        if ((int)threadIdx.x < s) red[threadIdx.x] = fmaxf(red[threadIdx.x], red[threadIdx.x + s]);
        __syncthreads();
    }
    if (threadIdx.x == 0) scal[0] = red[0];
}
__global__ void smax_psum_kernel(const float* __restrict__ gl, const float* __restrict__ scal,
                                 float* __restrict__ psum) {
    __shared__ float red[256];
    float gmax = scal[0];
    float s = 0.0f;
    for (int i = blockIdx.x * blockDim.x + threadIdx.x; i < N_NODES; i += gridDim.x * blockDim.x)
        s += expf(gl[i] - gmax);
    red[threadIdx.x] = s; __syncthreads();
    for (int t = 128; t; t >>= 1) {
        if ((int)threadIdx.x < t) red[threadIdx.x] += red[threadIdx.x + t];
        __syncthreads();
    }
    if (threadIdx.x == 0) psum[blockIdx.x] = red[0];
}
__global__ void smax_fsum_kernel(const float* __restrict__ psum, float* __restrict__ scal) {
    __shared__ float red[256];
    red[threadIdx.x] = psum[threadIdx.x]; __syncthreads();
    for (int t = 128; t; t >>= 1) {
        if ((int)threadIdx.x < t) red[threadIdx.x] += red[threadIdx.x + t];
        __syncthreads();
    }
    if (threadIdx.x == 0) { scal[1] = red[0]; scal[2] = 1.0f / red[0]; }
}

// ===================== pooling =====================
__device__ inline int lower_bound_i(const int* a, int n, int key) {
    int lo = 0, hi = n;
    while (lo < hi) {
        int mid = (lo + hi) >> 1;
        if (a[mid] < key) lo = mid + 1; else hi = mid;
    }
    return lo;
}
__global__ void pool_kernel(const float* __restrict__ dx, const int* __restrict__ batch,
                            float* __restrict__ pooled) {
    int g = blockIdx.x;
    int lo = lower_bound_i(batch, N_NODES, g);
    int hi = lower_bound_i(batch, N_NODES, g + 1);
    int lane = threadIdx.x & 63;
    int w = threadIdx.x >> 6;
    float acc = 0.0f;
    for (int n = lo + w; n < hi; n += 4) acc += dx[n * EMB + lane];
    __shared__ float red[4][EMB];
    red[w][lane] = acc; __syncthreads();
    if (threadIdx.x < EMB) {
        float s = red[0][threadIdx.x] + red[1][threadIdx.x] + red[2][threadIdx.x] + red[3][threadIdx.x];
        int cnt = hi - lo;
        pooled[g * EMB + threadIdx.x] = cnt > 0 ? s / (float)cnt : 0.0f;
    }
}

// ===================== graph MLP =====================
__global__ void graph_mlp_kernel(const float* __restrict__ pooled,
                                 const float* __restrict__ wc1, const float* __restrict__ bc1,
                                 const float* __restrict__ wc2, const float* __restrict__ bc2,
                                 float* __restrict__ alphag) {
    int g = blockIdx.x;
    __shared__ float p[EMB];
    __shared__ float h[EMB];
    if (threadIdx.x < EMB) p[threadIdx.x] = pooled[g * EMB + threadIdx.x];
    __syncthreads();
    if (threadIdx.x < EMB) {
        int j = threadIdx.x;
        float a = bc1[j];
        for (int c = 0; c < EMB; ++c) a += p[c] * wc1[c * EMB + j];
        h[j] = fmaxf(a, 0.0f);
    }
    __syncthreads();
    int o = threadIdx.x;   // 0..127
    float a = bc2[o];
    for (int j = 0; j < EMB; ++j) a += h[j] * wc2[j * 256 + o];
    alphag[g * 128 + o] = tanhf(a);
}

// ===================== final =====================
__global__ void final_kernel(const float* __restrict__ x, const int* __restrict__ batch,
                             const float* __restrict__ gl, const float* __restrict__ scal,
                             const float* __restrict__ alphag, float* __restrict__ out) {
    int n = (blockIdx.x * blockDim.x + threadIdx.x) >> 6;
    if (n >= N_NODES) return;
    int lane = threadIdx.x & 63;
    int g = batch[n];
    float gamma = expf(gl[n] - scal[0]) * scal[2];
    float a0 = alphag[g * 128 + lane];
    float a1 = alphag[g * 128 + 64 + lane];
    float t = gamma * (x[n * EMB + lane] + 1.0f);
    out[n * EMB + lane] = fmaxf(a0 * t, a1 * t);
}

extern "C" void kernel_launch(void* const* d_in, const int* in_sizes, int n_in,
                              void* d_out, int out_size, void* d_ws, size_t ws_size,
                              hipStream_t stream) {
    const float* x     = (const float*)d_in[0];
    const int*   ei    = (const int*)d_in[1];
    const int*   batch = (const int*)d_in[3];
    const float* wn1 = (const float*)d_in[4];
    const float* bn1 = (const float*)d_in[5];
    const float* wn2 = (const float*)d_in[6];
    const float* bn2 = (const float*)d_in[7];
    const float* wc1 = (const float*)d_in[8];
    const float* bc1 = (const float*)d_in[9];
    const float* wc2 = (const float*)d_in[10];
    const float* bc2 = (const float*)d_in[11];
    float* out = (float*)d_out;

    char* wsb = (char*)d_ws;
    float* dx     = (float*)wsb;                        // 6,400,000 f (aliases gpairs)
    float* gl     = dx + (size_t)N_NODES * EMB;         // 100,000
    float* dinv   = gl + N_NODES;                       // 100,000
    float* pooled = dinv + N_NODES;                     // 32,768
    float* alphag = pooled + NUM_GRAPHS * EMB;          // 65,536
    float* pmax   = alphag + NUM_GRAPHS * 128;          // 512
    float* psum   = pmax + 512;                         // 512
    float* scal   = psum + 512;                         // 4
    int* indeg    = (int*)(scal + 4);                   // 100,000
    int* rowstart = indeg + N_NODES;                    // 100,000
    int* bcur     = rowstart + N_NODES;                 // 512
    int* partials = bcur + 512;                         // 256
    int* ebuf     = partials + 256;                     // 3,200,000
    size_t needed = (size_t)((char*)(ebuf + N_EDGES) - wsb);
    unsigned* gpairs = (unsigned*)dx;                   // aliases dx (consumed before gather writes)

    if (ws_size >= needed) {
        hipMemsetAsync(indeg, 0, N_NODES * sizeof(int), stream);
        hist_kernel<<<(N_EDGES + 255) / 256, 256, 0, stream>>>(ei, indeg);
        scanA_kernel<<<SCAN_NB, 256, 0, stream>>>(indeg, rowstart, partials);
        scanB_kernel<<<1, 256, 0, stream>>>(partials);
        scanC_kernel<<<(N_NODES + 255) / 256, 256, 0, stream>>>(rowstart, bcur, partials, indeg, dinv);
        partition_kernel<<<PBLOCKS, 256, 0, stream>>>(ei, bcur, gpairs);
        bscatter_kernel<<<NB, 256, 0, stream>>>(gpairs, rowstart, ebuf);
        gather_mlp_kernel<<<(N_NODES * 64) / 256, 256, 0, stream>>>(ebuf, rowstart, indeg, dinv, x, dx,
                                                                    wn1, bn1, wn2, bn2, gl);
    } else {
        hipMemsetAsync(dx, 0, (size_t)N_NODES * EMB * sizeof(float), stream);
        init_deg_kernel<<<(N_NODES + 255) / 256, 256, 0, stream>>>(dinv);
        deg_kernel<<<(N_EDGES + 255) / 256, 256, 0, stream>>>(ei, dinv);
        dinv_kernel<<<(N_NODES + 255) / 256, 256, 0, stream>>>(dinv);
        agg_kernel<<<((size_t)N_EDGES * 64 + 255) / 256, 256, 0, stream>>>(ei, x, dinv, dx);
        diffuse_kernel<<<(N_NODES * (EMB / 4) + 255) / 256, 256, 0, stream>>>(x, dinv, dx);
        node_mlp_kernel<<<N_NODES / 4, 256, 0, stream>>>(dx, wn1, bn1, wn2, bn2, gl);
    }

    smax_pmax_kernel<<<256, 256, 0, stream>>>(gl, pmax);
    smax_fmax_kernel<<<1, 256, 0, stream>>>(pmax, scal);
    smax_psum_kernel<<<256, 256, 0, stream>>>(gl, scal, psum);
    smax_fsum_kernel<<<1, 256, 0, stream>>>(psum, scal);
    pool_kernel<<<NUM_GRAPHS, 256, 0, stream>>>(dx, batch, pooled);
    graph_mlp_kernel<<<NUM_GRAPHS, 128, 0, stream>>>(pooled, wc1, bc1, wc2, bc2, alphag);
    final_kernel<<<N_NODES / 4, 256, 0, stream>>>(x, batch, gl, scal, alphag, out);
}